// Round 5
// baseline (1696.486 us; speedup 1.0000x reference)
//
#include <hip/hip_runtime.h>

// GRU B=256,T=2000,I=23,H=128 (r,z,n order) + mean over T.
// 1 batch row per block, 256 blocks (1/CU), 1024 threads = 16 waves (4/SIMD).
// Slot sl = wave*4 + (l>>4) in [0,64); slot owns j in {2sl, 2sl+1}.
// Lane kt = l&15 covers k = kt*8..+8. Per-slot 8 accumulators = the 8 sums
// {r(j0),r(j1),z(j0),z(j1),ghn(j0),ghn(j1),gxn(j0),gxn(j1)} (acc-slot q = c*2+e,
// c=class r/z/nh/nx, e=which j). acc[i] <-> q = i^p, p = bitrev3(l&7), so the
// 4-level XOR fold (verified in r3) totals all 8 sums across the 16 kt lanes.
// Gathers are quad_perm DPP: q^2 at lane^2, q^4 at lane^1, q^6 at lane^3.
// Epilogue runs IN-LANE (h_old in a register) -> ONE barrier per step.
// R4 BUG FIX: lanes kt>=7 own exactly ONE x element (xi0); r4's
// `xi0+1>=Ii` test wrongly let kt=7..14 also accumulate x[xi0+1],
// double-counting x[15..22]. Restored the xn<2 => wx1=0 rule.

#define Bb 256
#define Tt 2000
#define Ii 23
#define Hh 128

template <int ctrl>
__device__ __forceinline__ float dpp_movf(float v) {
    int r = __builtin_amdgcn_update_dpp(0, __builtin_bit_cast(int, v),
                                        ctrl, 0xf, 0xf, true);
    return __builtin_bit_cast(float, r);
}

__global__ __launch_bounds__(1024, 4)
void gru_fused(const float* __restrict__ x,     // [B,T,I]
               const float* __restrict__ W_ih,  // [3H,I]
               const float* __restrict__ W_hh,  // [3H,H]
               const float* __restrict__ b_ih,  // [3H]
               const float* __restrict__ b_hh,  // [3H]
               float* __restrict__ out)         // [B,H]
{
    const int b   = blockIdx.x;
    const int t   = threadIdx.x;
    const int wid = t >> 6;
    const int l   = t & 63;
    const int kt  = l & 15;                 // k in [kt*8, kt*8+8)
    const int gl  = l >> 4;
    const int sl  = wid * 4 + gl;           // 0..63
    const int p   = ((l & 1) << 2) | (l & 2) | ((l >> 2) & 1); // bitrev3

    __shared__ __align__(16) float hbuf[16 * 12]; // h[k=8a+c] at [a*12+c] (pad 12 -> 2-way)
    __shared__ float xbuf[2][24];                 // double-buffered x_t, [23]=0 pad

    // ---- weights: acc i <-> quantity q = i^p; q = c*2+e; j = 2*sl+e ----
    const int xi0 = (kt < 7) ? kt * 2 : kt + 7;   // lane's x indices; kt<7 owns 2, else 1
    const bool two_x = (kt < 7);
    float whh[8][8];
    float wx0[8], wx1[8];
    #pragma unroll
    for (int i = 0; i < 8; ++i) {
        const int q = i ^ p;
        const int e = q & 1, c = q >> 1;
        const int jq = 2 * sl + e;
        const int row = (c == 0) ? jq : (c == 1) ? (Hh + jq) : (2 * Hh + jq);
        #pragma unroll
        for (int k = 0; k < 8; ++k)
            whh[i][k] = (c == 3) ? 0.0f : W_hh[(size_t)row * Hh + kt * 8 + k];
        // x-side: r,z fold x into same acc; nx gets only x; nh gets none
        wx0[i] = (c == 2) ? 0.0f : W_ih[(size_t)row * Ii + xi0];
        wx1[i] = (c == 2 || !two_x) ? 0.0f : W_ih[(size_t)row * Ii + xi0 + 1];
    }

    // per-lane j (valid on r-lanes; harmless elsewhere)
    const int ej = (l >> 2) & 1;
    const int j  = 2 * sl + ej;
    const float bias_r  = b_ih[j] + b_hh[j];
    const float bias_z  = b_ih[Hh + j] + b_hh[Hh + j];
    const float bias_nh = b_hh[2 * Hh + j];
    const float bias_nx = b_ih[2 * Hh + j];
    const bool writer = ((l & 3) == 0) && ((l & 8) == 0);

    const float* xrow = x + (size_t)b * Tt * Ii;

    // ---- init ----
    if (t < 192) hbuf[t] = 0.0f;
    if (t < 23) xbuf[0][t] = xrow[t];
    if (t == 23) { xbuf[0][23] = 0.0f; xbuf[1][23] = 0.0f; }
    float h_reg = 0.0f, acc_mean = 0.0f;
    __syncthreads();

    for (int step = 0; step < Tt; ++step) {
        // prefetch next x_t (latency hidden under the dot)
        float xpref = 0.0f;
        if (t < 23 && step + 1 < Tt) xpref = xrow[(size_t)(step + 1) * Ii + t];

        // ---- h tile: 8 f32 via 2x b128 (16 addrs x 4-lane broadcast) ----
        const float4 hA = *reinterpret_cast<const float4*>(&hbuf[kt * 12]);
        const float4 hB = *reinterpret_cast<const float4*>(&hbuf[kt * 12 + 4]);
        const float xa = xbuf[step & 1][xi0];
        const float xb = xbuf[step & 1][xi0 + 1];   // index <= 23 (pad)

        // ---- MACs: x-proj init + 8x8 recurrent tile ----
        float a0[8];
        #pragma unroll
        for (int i = 0; i < 8; ++i) a0[i] = fmaf(wx0[i], xa, wx1[i] * xb);
        const float hv[8] = {hA.x, hA.y, hA.z, hA.w, hB.x, hB.y, hB.z, hB.w};
        #pragma unroll
        for (int k = 0; k < 8; ++k) {
            #pragma unroll
            for (int i = 0; i < 8; ++i)
                a0[i] = fmaf(whh[i][k], hv[k], a0[i]);
        }

        // ---- fold across 16 kt lanes (xor1<->acc^4, xor2<->acc^2,
        //      xor4<->acc^1 (shfl), xor8 duplicate) ----
        float f0 = a0[0] + dpp_movf<0xB1>(a0[4]);
        float f1 = a0[1] + dpp_movf<0xB1>(a0[5]);
        float f2 = a0[2] + dpp_movf<0xB1>(a0[6]);
        float f3 = a0[3] + dpp_movf<0xB1>(a0[7]);
        float c0 = f0 + dpp_movf<0x4E>(f2);
        float c1 = f1 + dpp_movf<0x4E>(f3);
        float d  = c0 + __shfl_xor(c1, 4, 64);
        float v  = d + dpp_movf<0x128>(d);
        // lane l now holds total for quantity q = p(l&7)

        // ---- gather the triple into the r-lanes (pure quad-perm DPP) ----
        float s_r = v + bias_r;                       // own quantity (q = e)
        float s_z = dpp_movf<0x4E>(v) + bias_z;       // q^2 at lane^2
        float ghn = dpp_movf<0xB1>(v) + bias_nh;      // q^4 at lane^1
        float gxn = dpp_movf<0x1B>(v) + bias_nx;      // q^6 at lane^3

        // ---- in-lane epilogue (redundant on non-r lanes, never written) ----
        float r = 1.0f / (1.0f + __expf(-s_r));
        float z = 1.0f / (1.0f + __expf(-s_z));
        float npre = fmaf(r, ghn, gxn);
        float n = 2.0f / (1.0f + __expf(-2.0f * npre)) - 1.0f;
        float h_new = fmaf(z, h_reg - n, n);
        acc_mean += h_new;
        h_reg = h_new;
        if (writer) hbuf[(j >> 3) * 12 + (j & 7)] = h_new;

        // stage next x into alternate buffer
        if (t < 23 && step + 1 < Tt) xbuf[(step + 1) & 1][t] = xpref;

        __syncthreads();   // the ONLY barrier per step
    }

    if (writer) out[(size_t)b * Hh + j] = acc_mean * (1.0f / Tt);
}

extern "C" void kernel_launch(void* const* d_in, const int* in_sizes, int n_in,
                              void* d_out, int out_size, void* d_ws, size_t ws_size,
                              hipStream_t stream) {
    const float* x    = (const float*)d_in[0];
    const float* W_ih = (const float*)d_in[1];
    const float* W_hh = (const float*)d_in[2];
    const float* b_ih = (const float*)d_in[3];
    const float* b_hh = (const float*)d_in[4];
    float* out = (float*)d_out;

    gru_fused<<<Bb, 1024, 0, stream>>>(x, W_ih, W_hh, b_ih, b_hh, out);
}